// Round 13
// baseline (47.489 us; speedup 1.0000x reference)
//
#include <hip/hip_runtime.h>
#include <hip/hip_fp16.h>

// Problem constants (match reference)
constexpr int Bc = 64;
constexpr int Nc = 32768;
constexpr int Kc = 128;
constexpr int Tc = 512;      // trajectory length
constexpr int TMAXc = 512;   // table time dim (== Tc)
constexpr int BK = Bc * Kc;  // 8192

typedef float f32x4 __attribute__((ext_vector_type(4)));
typedef float f32x2 __attribute__((ext_vector_type(2)));

// Workspace layout:
//   [0, 16777216)        table    (B,K,TMAX) half2 (4 B/slot)
//   [16777216, +4096)    partials 512 x float2
constexpr size_t TABLE_BYTES = (size_t)BK * TMAXc * 4;

constexpr int P1_HALF_BLOCKS = 2048;  // (32 b * 128 k) / 2 pairs
constexpr int P2_HALF_BLOCKS = 256;   // 32 b * 8 chunks (4096 items each)

// ---- p1 role: build table slices for 2 contiguous (b,k) pairs -------------
// boff selects the batch half. XCD affinity: b % 8 == blockgroup % 8.
__device__ __forceinline__ void p1_role(int j, int boff,
    const f32x4* __restrict__ traj4, uint2* __restrict__ table2)
{
    __shared__ __align__(16) float    stage[2 * Tc * 5];  // 20480 B
    __shared__ __align__(8)  unsigned tbl[2 * TMAXc];     //  4096 B

    const int xcd = j & 7;
    const int s   = j >> 3;                  // 0..255
    const int b   = boff + (((s >> 6) << 3) | xcd);   // 32 batches of the half
    const int k2  = s & 63;
    const int bk0 = (b << 7) | (k2 << 1);

    const f32x4* src = traj4 + (size_t)bk0 * 640;
    #pragma unroll
    for (int r = 0; r < 5; ++r) {            // 1280 f32x4 = exactly 5/thread
        int t = threadIdx.x + r * 256;
        ((f32x4*)stage)[t] = __builtin_nontemporal_load(&src[t]);
    }
    __syncthreads();

    #pragma unroll
    for (int r = 0; r < 4; ++r) {            // scatter 1024 records in LDS
        int t = threadIdx.x + r * 256;       // pair = t>>9
        float x  = stage[t * 5 + 0];
        float y  = stage[t * 5 + 1];
        float tv = stage[t * 5 + 4];
        int tau = __float2int_rn(tv * 10.0f);      // matches jnp.round(...)
        if ((unsigned)tau < (unsigned)TMAXc) {     // mode='drop'
            __half2 p = __floats2half2_rn(x, y);
            unsigned raw;
            __builtin_memcpy(&raw, &p, 4);
            tbl[((t >> 9) << 9) + tau] = raw;
        }
    }
    __syncthreads();

    uint2* dst = table2 + (size_t)bk0 * 256;
    #pragma unroll
    for (int r = 0; r < 2; ++r) {            // 512 uint2 = exactly 2/thread
        int t = threadIdx.x + r * 256;
        dst[t] = ((const uint2*)tbl)[t];
    }
}

// ---- p2 role: 4096 items, 16 gathers in flight, partial -> partials[pidx] --
// R7-proven config (measured best). NO fences/atomics (R4/R9: 45-80 us cost).
__device__ __forceinline__ void p2_role(int jj, int boff,
    const f32x2*    __restrict__ state2,
    const int*      __restrict__ tidx,
    const int*      __restrict__ uid,
    const unsigned* __restrict__ table,
    float2*         __restrict__ partials, int pbase_idx)
{
    const int xcd   = jj & 7;
    const int s     = jj >> 3;                 // 0..31
    const int b     = boff + (((s >> 3) << 3) | xcd);
    const int chunk = s & 7;                   // 0..7
    const int base  = (b << 15) + (chunk << 12);   // 4096 items per block
    const unsigned* tb = table + ((long long)b << 16);

    f32x2    sv[16];
    int      idv[16], tiv[16];
    unsigned tg[16];

    #pragma unroll
    for (int r = 0; r < 16; ++r) {
        int i = base + r * 256 + threadIdx.x;
        sv[r]  = __builtin_nontemporal_load(&state2[2 * (size_t)i]);  // xy only
        idv[r] = __builtin_nontemporal_load(&uid[i]);
        tiv[r] = __builtin_nontemporal_load(&tidx[i]);
    }
    #pragma unroll
    for (int r = 0; r < 16; ++r) {
        int obj = min(max(idv[r], 0), Kc - 1);
        int tcl = min(max(tiv[r], 0), TMAXc - 1);
        tg[r] = tb[(obj << 9) + tcl];
    }
    float sum = 0.0f, cnt = 0.0f;
    #pragma unroll
    for (int r = 0; r < 16; ++r) {
        __half2 p;
        __builtin_memcpy(&p, &tg[r], 4);
        float tx = __low2float(p);
        float ty = __high2float(p);
        if (idv[r] >= 0) {
            sum += fabsf(sv[r].x - tx) + fabsf(sv[r].y - ty);
            cnt += 1.0f;
        }
    }

    #pragma unroll
    for (int off = 32; off > 0; off >>= 1) {
        sum += __shfl_down(sum, off, 64);
        cnt += __shfl_down(cnt, off, 64);
    }
    __shared__ float2 lred[4];
    const int lane = threadIdx.x & 63;
    const int w    = threadIdx.x >> 6;
    if (lane == 0) lred[w] = make_float2(sum, cnt);
    __syncthreads();
    if (threadIdx.x == 0) {
        float s2 = 0.0f, c2 = 0.0f;
        #pragma unroll
        for (int q = 0; q < 4; ++q) { s2 += lred[q].x; c2 += lred[q].y; }
        partials[pbase_idx + jj] = make_float2(s2, c2);
    }
}

// ---- k1: build half0 table ------------------------------------------------
__global__ __launch_bounds__(256) void build_half_k(
    const f32x4* __restrict__ traj4, uint2* __restrict__ table2)
{
    p1_role(blockIdx.x, 0, traj4, table2);
}

// ---- k2: build half1 table WHILE gathering half0 --------------------------
// HBM-bound p1 blocks and MSHR/latency-bound p2 blocks run concurrently.
// half0's table is complete (k1 kernel boundary); b%8 affinity holds for both
// roles (2048 % 8 == 0).
__global__ __launch_bounds__(256) void mixed_k(
    const f32x4* __restrict__ traj4, uint2* __restrict__ table2,
    const f32x2* __restrict__ state2,
    const int*   __restrict__ tidx,
    const int*   __restrict__ uid,
    float2*      __restrict__ partials)
{
    if (blockIdx.x < P1_HALF_BLOCKS) {
        p1_role(blockIdx.x, 32, traj4, table2);
    } else {
        p2_role(blockIdx.x - P1_HALF_BLOCKS, 0, state2, tidx, uid,
                (const unsigned*)table2, partials, 0);
    }
}

// ---- k3: gather half1 -----------------------------------------------------
__global__ __launch_bounds__(256) void gather_half_k(
    const f32x2* __restrict__ state2,
    const int*   __restrict__ tidx,
    const int*   __restrict__ uid,
    const uint2* __restrict__ table2,
    float2*      __restrict__ partials)
{
    p2_role(blockIdx.x, 32, state2, tidx, uid,
            (const unsigned*)table2, partials, P2_HALF_BLOCKS);
}

// ---- k4: deterministic final reduce -> loss -------------------------------
__global__ __launch_bounds__(512) void final_reduce_k(
    const float2* __restrict__ partials, float* __restrict__ out)
{
    float s, c;
    {
        float2 p = partials[threadIdx.x];   // exactly 512 partials
        s = p.x; c = p.y;
    }
    #pragma unroll
    for (int off = 32; off > 0; off >>= 1) {
        s += __shfl_down(s, off, 64);
        c += __shfl_down(c, off, 64);
    }
    __shared__ float2 lds[8];
    int lane = threadIdx.x & 63;
    int w    = threadIdx.x >> 6;
    if (lane == 0) lds[w] = make_float2(s, c);
    __syncthreads();
    if (threadIdx.x == 0) {
        float s2 = 0.0f, c2 = 0.0f;
        #pragma unroll
        for (int q = 0; q < 8; ++q) { s2 += lds[q].x; c2 += lds[q].y; }
        out[0] = s2 / c2;
    }
}

extern "C" void kernel_launch(void* const* d_in, const int* in_sizes, int n_in,
                              void* d_out, int out_size, void* d_ws, size_t ws_size,
                              hipStream_t stream) {
    const f32x2* state2 = (const f32x2*)d_in[0];   // (B,N,4) f32
    const int*   tidx   = (const int*)  d_in[1];   // (B,N)   i32
    const int*   uid    = (const int*)  d_in[2];   // (B,N)   i32
    const f32x4* traj4  = (const f32x4*)d_in[3];   // (B,K,T,5) f32
    float* out = (float*)d_out;

    uint2*  table    = (uint2*)d_ws;
    float2* partials = (float2*)((char*)d_ws + TABLE_BYTES);

    build_half_k <<<P1_HALF_BLOCKS, 256, 0, stream>>>(traj4, table);
    mixed_k      <<<P1_HALF_BLOCKS + P2_HALF_BLOCKS, 256, 0, stream>>>(
                     traj4, table, state2, tidx, uid, partials);
    gather_half_k<<<P2_HALF_BLOCKS, 256, 0, stream>>>(state2, tidx, uid,
                                                      table, partials);
    final_reduce_k<<<1, 512, 0, stream>>>(partials, out);
}

// Round 14
// 44.117 us; speedup vs baseline: 1.0764x; 1.0764x over previous
//
#include <hip/hip_runtime.h>
#include <hip/hip_fp16.h>

// Problem constants (match reference)
constexpr int Bc = 64;
constexpr int Nc = 32768;
constexpr int Kc = 128;
constexpr int Tc = 512;      // trajectory length
constexpr int TMAXc = 512;   // table time dim (== Tc)
constexpr int BK = Bc * Kc;  // 8192

typedef float f32x4 __attribute__((ext_vector_type(4)));
typedef float f32x2 __attribute__((ext_vector_type(2)));

// Workspace layout:
//   [0, 16777216)        table    (B,K,TMAX) half2 (4 B/slot)
//   [16777216, +4096)    partials 512 x float2
constexpr size_t TABLE_BYTES = (size_t)BK * TMAXc * 4;
constexpr int NBLK1 = BK / 2;   // 4096 blocks, 2 (b,k) pairs each
constexpr int NBLK2 = 512;      // measured-best p2 geometry (R7): 16 items/thread

// ---------------- Phase 1: scatter traj xy into (B,K,TMAX) half2 table ------
// Two contiguous (b,k) pairs per block (exact 5-iter load balance), XCD
// affinity b % 8 == blockIdx % 8 so each b-slice is built in one XCD's L2.
// times is a permutation of 0..511 per (b,k): every slot is written.
// Measured ~14 us = its 101 MB roofline (R9 decomposition) — done.
__global__ __launch_bounds__(256) void build_table_k(
    const f32x4* __restrict__ traj4,   // (B,K,T,5) viewed as f32x4[BK*640]
    uint2* __restrict__ table2)        // (B,K,TMAX) half2 viewed as uint2[BK*256]
{
    __shared__ __align__(16) float    stage[2 * Tc * 5];  // 20480 B
    __shared__ __align__(8)  unsigned tbl[2 * TMAXc];     //  4096 B

    const int j   = blockIdx.x;
    const int xcd = j & 7;
    const int s   = j >> 3;                  // 0..511
    const int b   = ((s >> 6) << 3) | xcd;   // 0..63, b%8 == xcd
    const int k2  = s & 63;                  // pair-of-k index
    const int bk0 = (b << 7) | (k2 << 1);    // first of two contiguous (b,k)

    // coalesced nt load: 1280 f32x4 per block = exactly 5 per thread
    const f32x4* src = traj4 + (size_t)bk0 * 640;
    #pragma unroll
    for (int r = 0; r < 5; ++r) {
        int t = threadIdx.x + r * 256;
        ((f32x4*)stage)[t] = __builtin_nontemporal_load(&src[t]);
    }
    __syncthreads();

    // scatter 1024 records within LDS
    #pragma unroll
    for (int r = 0; r < 4; ++r) {
        int t = threadIdx.x + r * 256;         // 0..1023; pair = t>>9
        float x  = stage[t * 5 + 0];
        float y  = stage[t * 5 + 1];
        float tv = stage[t * 5 + 4];
        int tau = __float2int_rn(tv * 10.0f);      // matches jnp.round(...)
        if ((unsigned)tau < (unsigned)TMAXc) {     // mode='drop'
            __half2 p = __floats2half2_rn(x, y);
            unsigned raw;
            __builtin_memcpy(&raw, &p, 4);
            tbl[((t >> 9) << 9) + tau] = raw;
        }
    }
    __syncthreads();

    // coalesced cached store: 512 uint2 = exactly 2 per thread
    uint2* dst = table2 + (size_t)bk0 * 256;
    #pragma unroll
    for (int r = 0; r < 2; ++r) {
        int t = threadIdx.x + r * 256;
        dst[t] = ((const uint2*)tbl)[t];
    }
}

// ---------------- Phase 2: gather + per-block partial reduction -------------
// R7 measured-best geometry (512 blocks x 16 items/thread). Single delta vs
// R7: gathers are ALSO nt (evict-first) — each random 4 B gather misses the
// 32 KB L1 ~88% of the time (256 KB working set) and pulls a 128 B line; nt
// avoids the L1 allocation churn. XCD affinity keeps gathers in local L2.
// NO fences/atomics (R4/R9: device-scope release costs 45-80 us here).
__global__ __launch_bounds__(256) void gather_reduce_k(
    const f32x2*    __restrict__ state2,  // (B,N,4) viewed as f32x2 pairs
    const int*      __restrict__ tidx,    // (B,N)
    const int*      __restrict__ uid,     // (B,N)
    const unsigned* __restrict__ table,   // (B,K,TMAX) half2 as u32
    float2*         __restrict__ partials)
{
    const int j     = blockIdx.x;
    const int xcd   = j & 7;
    const int s     = j >> 3;                 // 0..63
    const int b     = ((s >> 3) << 3) | xcd;  // 0..63, b%8 == xcd
    const int chunk = s & 7;                  // 0..7
    const int base  = (b << 15) + (chunk << 12);   // 4096 items per block
    const unsigned* tb = table + ((long long)b << 16);

    f32x2    sv[16];
    int      idv[16], tiv[16];
    unsigned tg[16];

    // 1) stream loads (nt: read-once)
    #pragma unroll
    for (int r = 0; r < 16; ++r) {
        int i = base + r * 256 + threadIdx.x;
        sv[r]  = __builtin_nontemporal_load(&state2[2 * (size_t)i]);  // xy only
        idv[r] = __builtin_nontemporal_load(&uid[i]);
        tiv[r] = __builtin_nontemporal_load(&tidx[i]);
    }
    // 2) 16 independent unconditional gathers (clamped addr is always valid)
    #pragma unroll
    for (int r = 0; r < 16; ++r) {
        int obj = min(max(idv[r], 0), Kc - 1);
        int tcl = min(max(tiv[r], 0), TMAXc - 1);
        tg[r] = __builtin_nontemporal_load(&tb[(obj << 9) + tcl]);
    }
    // 3) predicated accumulate
    float sum = 0.0f, cnt = 0.0f;
    #pragma unroll
    for (int r = 0; r < 16; ++r) {
        __half2 p;
        __builtin_memcpy(&p, &tg[r], 4);
        float tx = __low2float(p);
        float ty = __high2float(p);
        if (idv[r] >= 0) {
            sum += fabsf(sv[r].x - tx) + fabsf(sv[r].y - ty);
            cnt += 1.0f;
        }
    }

    // wave64 down-reduce, then cross-wave via LDS
    #pragma unroll
    for (int off = 32; off > 0; off >>= 1) {
        sum += __shfl_down(sum, off, 64);
        cnt += __shfl_down(cnt, off, 64);
    }
    __shared__ float2 lred[4];
    const int lane = threadIdx.x & 63;
    const int w    = threadIdx.x >> 6;
    if (lane == 0) lred[w] = make_float2(sum, cnt);
    __syncthreads();
    if (threadIdx.x == 0) {
        float s2 = 0.0f, c2 = 0.0f;
        #pragma unroll
        for (int q = 0; q < 4; ++q) { s2 += lred[q].x; c2 += lred[q].y; }
        partials[j] = make_float2(s2, c2);
    }
}

// ---------------- Phase 3: deterministic final reduce -> loss ---------------
__global__ __launch_bounds__(512) void final_reduce_k(
    const float2* __restrict__ partials, float* __restrict__ out)
{
    float s, c;
    {
        float2 p = partials[threadIdx.x];   // exactly 512 partials
        s = p.x; c = p.y;
    }
    #pragma unroll
    for (int off = 32; off > 0; off >>= 1) {
        s += __shfl_down(s, off, 64);
        c += __shfl_down(c, off, 64);
    }
    __shared__ float2 lds[8];
    int lane = threadIdx.x & 63;
    int w    = threadIdx.x >> 6;
    if (lane == 0) lds[w] = make_float2(s, c);
    __syncthreads();
    if (threadIdx.x == 0) {
        float s2 = 0.0f, c2 = 0.0f;
        #pragma unroll
        for (int q = 0; q < 8; ++q) { s2 += lds[q].x; c2 += lds[q].y; }
        out[0] = s2 / c2;
    }
}

extern "C" void kernel_launch(void* const* d_in, const int* in_sizes, int n_in,
                              void* d_out, int out_size, void* d_ws, size_t ws_size,
                              hipStream_t stream) {
    const f32x2* state2 = (const f32x2*)d_in[0];   // (B,N,4) f32
    const int*   tidx   = (const int*)  d_in[1];   // (B,N)   i32
    const int*   uid    = (const int*)  d_in[2];   // (B,N)   i32
    const f32x4* traj4  = (const f32x4*)d_in[3];   // (B,K,T,5) f32
    float* out = (float*)d_out;

    unsigned* table    = (unsigned*)d_ws;
    float2*   partials = (float2*)((char*)d_ws + TABLE_BYTES);

    build_table_k  <<<NBLK1, 256, 0, stream>>>(traj4, (uint2*)table);
    gather_reduce_k<<<NBLK2, 256, 0, stream>>>(state2, tidx, uid, table, partials);
    final_reduce_k <<<1, 512, 0, stream>>>(partials, out);
}

// Round 15
// 39.111 us; speedup vs baseline: 1.2142x; 1.1280x over previous
//
#include <hip/hip_runtime.h>
#include <hip/hip_fp16.h>

// Problem constants (match reference)
constexpr int Bc = 64;
constexpr int Nc = 32768;
constexpr int Kc = 128;
constexpr int Tc = 512;      // trajectory length
constexpr int TMAXc = 512;   // table time dim (== Tc)
constexpr int BK = Bc * Kc;  // 8192

typedef float f32x4 __attribute__((ext_vector_type(4)));
typedef float f32x2 __attribute__((ext_vector_type(2)));

// Workspace layout:
//   [0, 16777216)        table    (B,K,TMAX) half2 (4 B/slot)
//   [16777216, +4096)    partials 512 x float2
constexpr size_t TABLE_BYTES = (size_t)BK * TMAXc * 4;
constexpr int NBLK1 = BK / 2;   // 4096 blocks, 2 (b,k) pairs each
constexpr int NBLK2 = 512;      // measured-best p2 geometry: 16 items/thread

// ---------------- Phase 1: scatter traj xy into (B,K,TMAX) half2 table ------
// Two contiguous (b,k) pairs per block (exact 5-iter load balance), XCD
// affinity b % 8 == blockIdx % 8 so each b-slice is built in one XCD's L2.
// times is a permutation of 0..511 per (b,k): every slot is written.
// Measured ~14 us = its 101 MB HBM roofline (R9 decomposition).
__global__ __launch_bounds__(256) void build_table_k(
    const f32x4* __restrict__ traj4,   // (B,K,T,5) viewed as f32x4[BK*640]
    uint2* __restrict__ table2)        // (B,K,TMAX) half2 viewed as uint2[BK*256]
{
    __shared__ __align__(16) float    stage[2 * Tc * 5];  // 20480 B
    __shared__ __align__(8)  unsigned tbl[2 * TMAXc];     //  4096 B

    const int j   = blockIdx.x;
    const int xcd = j & 7;
    const int s   = j >> 3;                  // 0..511
    const int b   = ((s >> 6) << 3) | xcd;   // 0..63, b%8 == xcd
    const int k2  = s & 63;                  // pair-of-k index
    const int bk0 = (b << 7) | (k2 << 1);    // first of two contiguous (b,k)

    // coalesced nt load: 1280 f32x4 per block = exactly 5 per thread
    const f32x4* src = traj4 + (size_t)bk0 * 640;
    #pragma unroll
    for (int r = 0; r < 5; ++r) {
        int t = threadIdx.x + r * 256;
        ((f32x4*)stage)[t] = __builtin_nontemporal_load(&src[t]);
    }
    __syncthreads();

    // scatter 1024 records within LDS
    #pragma unroll
    for (int r = 0; r < 4; ++r) {
        int t = threadIdx.x + r * 256;         // 0..1023; pair = t>>9
        float x  = stage[t * 5 + 0];
        float y  = stage[t * 5 + 1];
        float tv = stage[t * 5 + 4];
        int tau = __float2int_rn(tv * 10.0f);      // matches jnp.round(...)
        if ((unsigned)tau < (unsigned)TMAXc) {     // mode='drop'
            __half2 p = __floats2half2_rn(x, y);
            unsigned raw;
            __builtin_memcpy(&raw, &p, 4);
            tbl[((t >> 9) << 9) + tau] = raw;
        }
    }
    __syncthreads();

    // coalesced cached store: 512 uint2 = exactly 2 per thread
    uint2* dst = table2 + (size_t)bk0 * 256;
    #pragma unroll
    for (int r = 0; r < 2; ++r) {
        int t = threadIdx.x + r * 256;
        dst[t] = ((const uint2*)tbl)[t];
    }
}

// ---------------- Phase 2: gather + per-block partial reduction -------------
// Measured-best geometry (512 blocks x 16 items/thread, ILP-saturated).
// CACHED gathers (R14: nt-gather cost +5 us — L1 hits matter). XCD affinity
// keeps each block's gathers inside its own XCD's L2 slice (R4 proof:
// gather FETCH == stream bytes only). NO fences/atomics (R4/R9: 45-80 us).
__global__ __launch_bounds__(256) void gather_reduce_k(
    const f32x2*    __restrict__ state2,  // (B,N,4) viewed as f32x2 pairs
    const int*      __restrict__ tidx,    // (B,N)
    const int*      __restrict__ uid,     // (B,N)
    const unsigned* __restrict__ table,   // (B,K,TMAX) half2 as u32
    float2*         __restrict__ partials)
{
    const int j     = blockIdx.x;
    const int xcd   = j & 7;
    const int s     = j >> 3;                 // 0..63
    const int b     = ((s >> 3) << 3) | xcd;  // 0..63, b%8 == xcd
    const int chunk = s & 7;                  // 0..7
    const int base  = (b << 15) + (chunk << 12);   // 4096 items per block
    const unsigned* tb = table + ((long long)b << 16);

    f32x2    sv[16];
    int      idv[16], tiv[16];
    unsigned tg[16];

    // 1) stream loads (nt: read-once, don't evict table from L2)
    #pragma unroll
    for (int r = 0; r < 16; ++r) {
        int i = base + r * 256 + threadIdx.x;
        sv[r]  = __builtin_nontemporal_load(&state2[2 * (size_t)i]);  // xy only
        idv[r] = __builtin_nontemporal_load(&uid[i]);
        tiv[r] = __builtin_nontemporal_load(&tidx[i]);
    }
    // 2) 16 independent unconditional gathers (clamped addr is always valid)
    #pragma unroll
    for (int r = 0; r < 16; ++r) {
        int obj = min(max(idv[r], 0), Kc - 1);
        int tcl = min(max(tiv[r], 0), TMAXc - 1);
        tg[r] = tb[(obj << 9) + tcl];
    }
    // 3) predicated accumulate
    float sum = 0.0f, cnt = 0.0f;
    #pragma unroll
    for (int r = 0; r < 16; ++r) {
        __half2 p;
        __builtin_memcpy(&p, &tg[r], 4);
        float tx = __low2float(p);
        float ty = __high2float(p);
        if (idv[r] >= 0) {
            sum += fabsf(sv[r].x - tx) + fabsf(sv[r].y - ty);
            cnt += 1.0f;
        }
    }

    // wave64 down-reduce, then cross-wave via LDS
    #pragma unroll
    for (int off = 32; off > 0; off >>= 1) {
        sum += __shfl_down(sum, off, 64);
        cnt += __shfl_down(cnt, off, 64);
    }
    __shared__ float2 lred[4];
    const int lane = threadIdx.x & 63;
    const int w    = threadIdx.x >> 6;
    if (lane == 0) lred[w] = make_float2(sum, cnt);
    __syncthreads();
    if (threadIdx.x == 0) {
        float s2 = 0.0f, c2 = 0.0f;
        #pragma unroll
        for (int q = 0; q < 4; ++q) { s2 += lred[q].x; c2 += lred[q].y; }
        partials[j] = make_float2(s2, c2);
    }
}

// ---------------- Phase 3: deterministic final reduce -> loss ---------------
__global__ __launch_bounds__(512) void final_reduce_k(
    const float2* __restrict__ partials, float* __restrict__ out)
{
    float s, c;
    {
        float2 p = partials[threadIdx.x];   // exactly 512 partials
        s = p.x; c = p.y;
    }
    #pragma unroll
    for (int off = 32; off > 0; off >>= 1) {
        s += __shfl_down(s, off, 64);
        c += __shfl_down(c, off, 64);
    }
    __shared__ float2 lds[8];
    int lane = threadIdx.x & 63;
    int w    = threadIdx.x >> 6;
    if (lane == 0) lds[w] = make_float2(s, c);
    __syncthreads();
    if (threadIdx.x == 0) {
        float s2 = 0.0f, c2 = 0.0f;
        #pragma unroll
        for (int q = 0; q < 8; ++q) { s2 += lds[q].x; c2 += lds[q].y; }
        out[0] = s2 / c2;
    }
}

extern "C" void kernel_launch(void* const* d_in, const int* in_sizes, int n_in,
                              void* d_out, int out_size, void* d_ws, size_t ws_size,
                              hipStream_t stream) {
    const f32x2* state2 = (const f32x2*)d_in[0];   // (B,N,4) f32
    const int*   tidx   = (const int*)  d_in[1];   // (B,N)   i32
    const int*   uid    = (const int*)  d_in[2];   // (B,N)   i32
    const f32x4* traj4  = (const f32x4*)d_in[3];   // (B,K,T,5) f32
    float* out = (float*)d_out;

    unsigned* table    = (unsigned*)d_ws;
    float2*   partials = (float2*)((char*)d_ws + TABLE_BYTES);

    build_table_k  <<<NBLK1, 256, 0, stream>>>(traj4, (uint2*)table);
    gather_reduce_k<<<NBLK2, 256, 0, stream>>>(state2, tidx, uid, table, partials);
    final_reduce_k <<<1, 512, 0, stream>>>(partials, out);
}